// Round 4
// baseline (2998.448 us; speedup 1.0000x reference)
//
#include <hip/hip_runtime.h>

constexpr int G  = 8;
constexpr int NN = 50000;
constexpr int EE = 800000;
constexpr int F  = 128;

typedef float  float4_t __attribute__((ext_vector_type(4)));
typedef float  f32x4    __attribute__((ext_vector_type(4)));
typedef __bf16 bf16x8   __attribute__((ext_vector_type(8)));

// ---------------- graph structure build (unchanged from r3; next-round target) ----

__global__ __launch_bounds__(256) void deg_kernel(const int* __restrict__ edges,
                                                  int* __restrict__ deg, int gbase) {
  int gw = blockIdx.y;
  size_t ebase = ((size_t)(gbase + gw) * 2 + 1) * EE;   // dst half
  int e = blockIdx.x * 256 + threadIdx.x;
  int dst = edges[ebase + e];
  atomicAdd(&deg[gw * NN + dst], 1);
}

__global__ __launch_bounds__(1024) void scan_kernel(int* __restrict__ deg, int* __restrict__ row_off,
                                                    float* __restrict__ dinv) {
  int gw  = blockIdx.x;
  int tid = threadIdx.x;
  int lane = tid & 63, wid = tid >> 6;
  __shared__ int wsum[16];
  __shared__ int carry_s;
  if (tid == 0) carry_s = 0;
  __syncthreads();
  int*   dg = deg + gw * NN;
  int*   ro = row_off + gw * (NN + 1);
  float* dv = dinv + gw * NN;
  for (int base = 0; base < NN; base += 1024) {
    int i = base + tid;
    int v = 0;
    if (i < NN) {
      v = dg[i];
      dv[i] = rsqrtf((float)v + 1.0f);
      dg[i] = 0;
    }
    int incl = v;
    #pragma unroll
    for (int off = 1; off < 64; off <<= 1) {
      int t = __shfl_up(incl, off);
      if (lane >= off) incl += t;
    }
    if (lane == 63) wsum[wid] = incl;
    __syncthreads();
    if (tid == 0) {
      int s = 0;
      #pragma unroll
      for (int w = 0; w < 16; ++w) { int t = wsum[w]; wsum[w] = s; s += t; }
    }
    __syncthreads();
    int excl = carry_s + wsum[wid] + (incl - v);
    if (i < NN) ro[i] = excl;
    __syncthreads();
    if (tid == 1023) carry_s = excl + v;
    __syncthreads();
  }
  if (tid == 0) ro[NN] = carry_s;
}

__global__ __launch_bounds__(256) void fill_kernel(const int* __restrict__ edges,
                                                   int* __restrict__ cursor, const int* __restrict__ row_off,
                                                   int* __restrict__ csr, int gbase) {
  int gw = blockIdx.y;
  size_t ebase = (size_t)(gbase + gw) * 2 * EE;
  int e = blockIdx.x * 256 + threadIdx.x;
  int src = edges[ebase + e];
  int dst = edges[ebase + EE + e];
  int slot = atomicAdd(&cursor[gw * NN + dst], 1);
  csr[(size_t)gw * EE + row_off[gw * (NN + 1) + dst] + slot] = src;
}

// ---------------- W^T hi/lo precompute (once per call, 3 layers) ----------------

__global__ __launch_bounds__(256) void wtprep_kernel(const float* __restrict__ W0,
                                                     const float* __restrict__ W1,
                                                     const float* __restrict__ W2,
                                                     __bf16* __restrict__ wt) {
  const float* Wl[3] = {W0, W1, W2};
  int l = blockIdx.x;
  const float* W = Wl[l];
  __bf16* hi = wt + (size_t)l * 2 * F * F;
  __bf16* lo = hi + F * F;
  for (int idx = threadIdx.x; idx < F * F; idx += 256) {
    int k = idx >> 7, c = idx & 127;
    float f = W[idx];
    __bf16 h = (__bf16)f;               // RNE to bf16
    hi[c * F + k] = h;                  // transposed: [col][k]
    lo[c * F + k] = (__bf16)(f - (float)h);
  }
}

// ---------------- fused (agg | load) + hi/lo-MFMA gemm ----------------
// mode 0: As rows <- hsrc rows (layer-0 input x)
// mode 1: As rows <- relu(dinv*(gather(hsrc)+self) + bias)   (prev layer's agg output)
// then: hdst[64-row block] = As @ W   via 3-term bf16 MFMA (hi*hi + hi*lo + lo*hi)

__global__ __launch_bounds__(256) void fused_kernel(const float* __restrict__ hsrc,
                                                    const int* __restrict__ cs,
                                                    const int* __restrict__ ro,
                                                    const float* __restrict__ dv,
                                                    const float* __restrict__ bias,
                                                    const __bf16* __restrict__ wt,
                                                    float* __restrict__ hdst,
                                                    int mode) {
  __shared__ float As[64][132];   // +4 pad: 2-way-max bank aliasing on frag reads
  int t = threadIdx.x;
  int row0 = blockIdx.x * 64;

  // ---- phase 1: produce 64 x 128 f32 rows in LDS ----
  if (mode == 0) {
    int lane4 = t & 31, r8 = t >> 5;
    #pragma unroll
    for (int i = 0; i < 8; ++i) {
      int r = r8 * 8 + i;
      int grow = row0 + r;
      float4_t v = {0.f, 0.f, 0.f, 0.f};
      if (grow < NN) v = *(const float4_t*)(hsrc + (size_t)grow * F + lane4 * 4);
      *(float4_t*)(&As[r][lane4 * 4]) = v;
    }
  } else {
    int grp = t >> 5, lane = t & 31;
    #pragma unroll
    for (int i = 0; i < 8; ++i) {
      int r = i * 8 + grp;
      int node = row0 + r;
      float4_t o = {0.f, 0.f, 0.f, 0.f};
      if (node < NN) {
        int e0 = ro[node], e1 = ro[node + 1];
        float di = dv[node];
        float4_t acc0 = *(const float4_t*)(hsrc + (size_t)node * F + lane * 4) * di;  // self
        float4_t acc1 = {0.f, 0.f, 0.f, 0.f};
        int e = e0;
        for (; e + 1 < e1; e += 2) {
          int s0 = cs[e], s1 = cs[e + 1];
          float d0 = dv[s0], d1 = dv[s1];
          acc0 += *(const float4_t*)(hsrc + (size_t)s0 * F + lane * 4) * d0;
          acc1 += *(const float4_t*)(hsrc + (size_t)s1 * F + lane * 4) * d1;
        }
        if (e < e1) {
          int s = cs[e];
          acc0 += *(const float4_t*)(hsrc + (size_t)s * F + lane * 4) * dv[s];
        }
        float4_t bb = *(const float4_t*)(bias + lane * 4);
        #pragma unroll
        for (int j = 0; j < 4; ++j) o[j] = fmaxf(fmaf(acc0[j] + acc1[j], di, bb[j]), 0.f);
      }
      *(float4_t*)(&As[r][lane * 4]) = o;
    }
  }
  __syncthreads();

  // ---- phase 2: 64x128 @ 128x128 MFMA; wave w owns rows [16w,16w+16) ----
  int w = t >> 6, l = t & 63;
  int arow = 16 * w + (l & 15);
  int kgrp = (l >> 4) * 8;                    // A & B share the same k-bijection
  bf16x8 ahi[4], alo[4];
  #pragma unroll
  for (int ks = 0; ks < 4; ++ks) {
    #pragma unroll
    for (int j = 0; j < 8; ++j) {
      float f = As[arow][ks * 32 + kgrp + j];
      __bf16 h = (__bf16)f;
      ahi[ks][j] = h;
      alo[ks][j] = (__bf16)(f - (float)h);
    }
  }
  const __bf16* wthi = wt;                    // [128 cols][128 k]
  const __bf16* wtlo = wt + F * F;
  #pragma unroll
  for (int tile = 0; tile < 8; ++tile) {
    f32x4 acc = {0.f, 0.f, 0.f, 0.f};
    int bcol = tile * 16 + (l & 15);
    #pragma unroll
    for (int ks = 0; ks < 4; ++ks) {
      bf16x8 bhi = *(const bf16x8*)(wthi + (size_t)bcol * F + ks * 32 + kgrp);
      bf16x8 blo = *(const bf16x8*)(wtlo + (size_t)bcol * F + ks * 32 + kgrp);
      acc = __builtin_amdgcn_mfma_f32_16x16x32_bf16(ahi[ks], bhi, acc, 0, 0, 0);
      acc = __builtin_amdgcn_mfma_f32_16x16x32_bf16(ahi[ks], blo, acc, 0, 0, 0);
      acc = __builtin_amdgcn_mfma_f32_16x16x32_bf16(alo[ks], bhi, acc, 0, 0, 0);
    }
    int drow0 = 16 * w + (l >> 4) * 4;        // D: col=lane&15, row=(lane>>4)*4+q (m89)
    #pragma unroll
    for (int q = 0; q < 4; ++q) {
      int grow = row0 + drow0 + q;
      if (grow < NN) hdst[(size_t)grow * F + tile * 16 + (l & 15)] = acc[q];
    }
  }
}

// ---------------- final aggregation (layer 2) -> d_out ----------------

__global__ __launch_bounds__(256) void agg_kernel(const float* __restrict__ h1, const int* __restrict__ cs,
                                                  const int* __restrict__ ro, const float* __restrict__ dv,
                                                  const float* __restrict__ bias, float* __restrict__ outg) {
  int grp = threadIdx.x >> 5, lane = threadIdx.x & 31;
  int node = blockIdx.x * 8 + grp;
  if (node >= NN) return;
  int e0 = ro[node];
  int e1 = ro[node + 1];
  float di = dv[node];
  float4_t acc0 = *(const float4_t*)(h1 + (size_t)node * F + lane * 4) * di;
  float4_t acc1 = {0.f, 0.f, 0.f, 0.f};
  int e = e0;
  for (; e + 1 < e1; e += 2) {
    int s0 = cs[e], s1 = cs[e + 1];
    float d0 = dv[s0], d1 = dv[s1];
    acc0 += *(const float4_t*)(h1 + (size_t)s0 * F + lane * 4) * d0;
    acc1 += *(const float4_t*)(h1 + (size_t)s1 * F + lane * 4) * d1;
  }
  if (e < e1) {
    int s = cs[e];
    acc0 += *(const float4_t*)(h1 + (size_t)s * F + lane * 4) * dv[s];
  }
  float4_t bb = *(const float4_t*)(bias + lane * 4);
  float4_t o;
  #pragma unroll
  for (int j = 0; j < 4; ++j) o[j] = fmaxf(fmaf(acc0[j] + acc1[j], di, bb[j]), 0.f);
  *(float4_t*)(outg + (size_t)node * F + lane * 4) = o;
}

// ---------------- host launch ----------------

extern "C" void kernel_launch(void* const* d_in, const int* in_sizes, int n_in,
                              void* d_out, int out_size, void* d_ws, size_t ws_size,
                              hipStream_t stream) {
  const float* x     = (const float*)d_in[0];
  const int*   edges = (const int*)d_in[1];
  const float* Ws[3] = {(const float*)d_in[2], (const float*)d_in[4], (const float*)d_in[6]};
  const float* bs[3] = {(const float*)d_in[3], (const float*)d_in[5], (const float*)d_in[7]};
  float* out = (float*)d_out;

  size_t sz_h  = (size_t)NN * F * 4;            // 25.6 MB activation ping buffer
  size_t sz_wt = (size_t)3 * 2 * F * F * 2;     // 196608 B: W^T hi/lo x 3 layers
  size_t sz_csr = (size_t)EE * 4;
  size_t sz_deg = (size_t)NN * 4;
  size_t sz_dv  = (size_t)NN * 4;
  size_t sz_ro  = (size_t)(NN + 1) * 4;
  size_t per_b  = sz_csr + sz_deg + sz_dv + sz_ro;
  size_t fixed  = sz_h + sz_wt;

  int CB = (int)((ws_size > fixed ? ws_size - fixed : 0) / per_b);
  if (CB < 1) CB = 1;
  if (CB > G) CB = G;

  char* p = (char*)d_ws;
  float*  hbuf    = (float*)p;   p += sz_h;
  __bf16* wt      = (__bf16*)p;  p += sz_wt;
  int*    csr     = (int*)p;     p += sz_csr * CB;
  int*    deg     = (int*)p;     p += sz_deg * CB;   // doubles as cursor
  float*  dinv    = (float*)p;   p += sz_dv  * CB;
  int*    row_off = (int*)p;

  wtprep_kernel<<<3, 256, 0, stream>>>(Ws[0], Ws[1], Ws[2], wt);

  int nblk = (NN + 63) / 64;   // 782

  for (int gb = 0; gb < G; gb += CB) {
    int Cg = G - gb < CB ? G - gb : CB;
    hipMemsetAsync(deg, 0, (size_t)Cg * NN * 4, stream);
    deg_kernel <<<dim3(EE / 256, Cg), 256, 0, stream>>>(edges, deg, gb);
    scan_kernel<<<Cg, 1024, 0, stream>>>(deg, row_off, dinv);
    fill_kernel<<<dim3(EE / 256, Cg), 256, 0, stream>>>(edges, deg, row_off, csr, gb);
    for (int gw = 0; gw < Cg; ++gw) {
      int g = gb + gw;
      const float* xg   = x   + (size_t)g * NN * F;
      float*       outg = out + (size_t)g * NN * F;
      const int*   csg  = csr + (size_t)gw * EE;
      const int*   rog  = row_off + (size_t)gw * (NN + 1);
      const float* dvg  = dinv + (size_t)gw * NN;
      // k0: hbuf = x @ W0
      fused_kernel<<<nblk, 256, 0, stream>>>(xg, csg, rog, dvg, bs[0], wt, hbuf, 0);
      // k1: outg = relu-agg(hbuf; b0) @ W1
      fused_kernel<<<nblk, 256, 0, stream>>>(hbuf, csg, rog, dvg, bs[0], wt + 2 * F * F, outg, 1);
      // k2: hbuf = relu-agg(outg; b1) @ W2
      fused_kernel<<<nblk, 256, 0, stream>>>(outg, csg, rog, dvg, bs[1], wt + 4 * F * F, hbuf, 1);
      // k3: outg = relu-agg(hbuf; b2)
      agg_kernel<<<(NN + 7) / 8, 256, 0, stream>>>(hbuf, csg, rog, dvg, bs[2], outg);
    }
  }
}

// Round 5
// 2017.664 us; speedup vs baseline: 1.4861x; 1.4861x over previous
//
#include <hip/hip_runtime.h>

constexpr int G  = 8;
constexpr int NN = 50000;
constexpr int EE = 800000;
constexpr int F  = 128;

typedef float  float4_t __attribute__((ext_vector_type(4)));
typedef float  f32x4    __attribute__((ext_vector_type(4)));
typedef __bf16 bf16x8   __attribute__((ext_vector_type(8)));
typedef unsigned short u16x4 __attribute__((ext_vector_type(4)));

__device__ inline float bf2f(unsigned short u) {
  union { unsigned int i; float f; } v; v.i = (unsigned int)u << 16; return v.f;
}
__device__ inline unsigned short f2bf(float f) {
  union { __bf16 b; unsigned short u; } v; v.b = (__bf16)f; return v.u;   // RNE
}
__device__ inline f32x4 cvt4(u16x4 v) {
  return (f32x4){bf2f(v[0]), bf2f(v[1]), bf2f(v[2]), bf2f(v[3])};
}

// ---------------- graph structure build (unchanged; r6 target: radix fill) ----

__global__ __launch_bounds__(256) void deg_kernel(const int* __restrict__ edges,
                                                  int* __restrict__ deg, int gbase) {
  int gw = blockIdx.y;
  size_t ebase = ((size_t)(gbase + gw) * 2 + 1) * EE;   // dst half
  int e = blockIdx.x * 256 + threadIdx.x;
  int dst = edges[ebase + e];
  atomicAdd(&deg[gw * NN + dst], 1);
}

__global__ __launch_bounds__(1024) void scan_kernel(int* __restrict__ deg, int* __restrict__ row_off,
                                                    float* __restrict__ dinv) {
  int gw  = blockIdx.x;
  int tid = threadIdx.x;
  int lane = tid & 63, wid = tid >> 6;
  __shared__ int wsum[16];
  __shared__ int carry_s;
  if (tid == 0) carry_s = 0;
  __syncthreads();
  int*   dg = deg + gw * NN;
  int*   ro = row_off + gw * (NN + 1);
  float* dv = dinv + gw * NN;
  for (int base = 0; base < NN; base += 1024) {
    int i = base + tid;
    int v = 0;
    if (i < NN) {
      v = dg[i];
      dv[i] = rsqrtf((float)v + 1.0f);
      dg[i] = 0;
    }
    int incl = v;
    #pragma unroll
    for (int off = 1; off < 64; off <<= 1) {
      int t = __shfl_up(incl, off);
      if (lane >= off) incl += t;
    }
    if (lane == 63) wsum[wid] = incl;
    __syncthreads();
    if (tid == 0) {
      int s = 0;
      #pragma unroll
      for (int w = 0; w < 16; ++w) { int t = wsum[w]; wsum[w] = s; s += t; }
    }
    __syncthreads();
    int excl = carry_s + wsum[wid] + (incl - v);
    if (i < NN) ro[i] = excl;
    __syncthreads();
    if (tid == 1023) carry_s = excl + v;
    __syncthreads();
  }
  if (tid == 0) ro[NN] = carry_s;
}

__global__ __launch_bounds__(256) void fill_kernel(const int* __restrict__ edges,
                                                   int* __restrict__ cursor, const int* __restrict__ row_off,
                                                   int* __restrict__ csr, int gbase) {
  int gw = blockIdx.y;
  size_t ebase = (size_t)(gbase + gw) * 2 * EE;
  int e = blockIdx.x * 256 + threadIdx.x;
  int src = edges[ebase + e];
  int dst = edges[ebase + EE + e];
  int slot = atomicAdd(&cursor[gw * NN + dst], 1);
  csr[(size_t)gw * EE + row_off[gw * (NN + 1) + dst] + slot] = src;
}

// ---------------- W^T hi/lo precompute ----------------

__global__ __launch_bounds__(256) void wtprep_kernel(const float* __restrict__ W0,
                                                     const float* __restrict__ W1,
                                                     const float* __restrict__ W2,
                                                     __bf16* __restrict__ wt) {
  const float* Wl[3] = {W0, W1, W2};
  int l = blockIdx.x;
  const float* W = Wl[l];
  __bf16* hi = wt + (size_t)l * 2 * F * F;
  __bf16* lo = hi + F * F;
  for (int idx = threadIdx.x; idx < F * F; idx += 256) {
    int k = idx >> 7, c = idx & 127;
    float f = W[idx];
    __bf16 h = (__bf16)f;
    hi[c * F + k] = h;                  // transposed: [col][k]
    lo[c * F + k] = (__bf16)(f - (float)h);
  }
}

// ---------------- batched hi/lo MFMA GEMM: h1[gw] = (act[g] @ W) * dinv[row] (bf16) ----

__global__ __launch_bounds__(256) void gemm_kernel(const float* __restrict__ act,
                                                   const __bf16* __restrict__ wt,
                                                   const float* __restrict__ dinv,
                                                   unsigned short* __restrict__ h1,
                                                   int gbase) {
  __shared__ float As[64][132];   // +4 pad
  int gw = blockIdx.y;
  const float* hg = act + (size_t)(gbase + gw) * NN * F;
  unsigned short* h1g = h1 + (size_t)gw * NN * F;
  const float* dv = dinv + (size_t)gw * NN;
  int t = threadIdx.x;
  int row0 = blockIdx.x * 64;

  int lane4 = t & 31, r8 = t >> 5;
  #pragma unroll
  for (int i = 0; i < 8; ++i) {
    int r = r8 * 8 + i;
    int grow = row0 + r;
    float4_t v = {0.f, 0.f, 0.f, 0.f};
    if (grow < NN) v = *(const float4_t*)(hg + (size_t)grow * F + lane4 * 4);
    *(float4_t*)(&As[r][lane4 * 4]) = v;
  }
  __syncthreads();

  int w = t >> 6, l = t & 63;
  int arow = 16 * w + (l & 15);
  int kgrp = (l >> 4) * 8;                    // A & B share the same k-bijection
  bf16x8 ahi[4], alo[4];
  #pragma unroll
  for (int ks = 0; ks < 4; ++ks) {
    #pragma unroll
    for (int j = 0; j < 8; ++j) {
      float f = As[arow][ks * 32 + kgrp + j];
      __bf16 h = (__bf16)f;
      ahi[ks][j] = h;
      alo[ks][j] = (__bf16)(f - (float)h);
    }
  }
  int drow0 = 16 * w + (l >> 4) * 4;          // D: col=lane&15, row=(lane>>4)*4+q (m89)
  float di4[4];
  #pragma unroll
  for (int q = 0; q < 4; ++q) {
    int grow = row0 + drow0 + q;
    di4[q] = (grow < NN) ? dv[grow] : 0.f;
  }
  const __bf16* wthi = wt;                    // [128 cols][128 k]
  const __bf16* wtlo = wt + F * F;
  #pragma unroll
  for (int tile = 0; tile < 8; ++tile) {
    f32x4 acc = {0.f, 0.f, 0.f, 0.f};
    int bcol = tile * 16 + (l & 15);
    #pragma unroll
    for (int ks = 0; ks < 4; ++ks) {
      bf16x8 bhi = *(const bf16x8*)(wthi + (size_t)bcol * F + ks * 32 + kgrp);
      bf16x8 blo = *(const bf16x8*)(wtlo + (size_t)bcol * F + ks * 32 + kgrp);
      acc = __builtin_amdgcn_mfma_f32_16x16x32_bf16(ahi[ks], bhi, acc, 0, 0, 0);
      acc = __builtin_amdgcn_mfma_f32_16x16x32_bf16(ahi[ks], blo, acc, 0, 0, 0);
      acc = __builtin_amdgcn_mfma_f32_16x16x32_bf16(alo[ks], bhi, acc, 0, 0, 0);
    }
    #pragma unroll
    for (int q = 0; q < 4; ++q) {
      int grow = row0 + drow0 + q;
      if (grow < NN) h1g[(size_t)grow * F + bcol] = f2bf(acc[q] * di4[q]);
    }
  }
}

// ---------------- batched aggregation: out[g] = relu(dinv*(self+gather) + b) ----
// h1 rows are pre-scaled by dinv[src]; 32 lanes/node, ILP-4 edge unroll.

__global__ __launch_bounds__(256) void agg_kernel(const unsigned short* __restrict__ h1,
                                                  const int* __restrict__ csr,
                                                  const int* __restrict__ row_off,
                                                  const float* __restrict__ dinv,
                                                  const float* __restrict__ bias,
                                                  float* __restrict__ out, int gbase) {
  int gw = blockIdx.y;
  const unsigned short* hg = h1 + (size_t)gw * NN * F;
  const int*   cs = csr + (size_t)gw * EE;
  const int*   ro = row_off + gw * (NN + 1);
  const float* dv = dinv + (size_t)gw * NN;
  float* outg = out + (size_t)(gbase + gw) * NN * F;

  int grp = threadIdx.x >> 5, lane = threadIdx.x & 31;
  int node = blockIdx.x * 8 + grp;
  if (node >= NN) return;
  int e0 = ro[node], e1 = ro[node + 1];
  float di = dv[node];
  f32x4 acc0 = cvt4(*(const u16x4*)(hg + (size_t)node * F + lane * 4));  // self (scaled)
  f32x4 acc1 = {0.f, 0.f, 0.f, 0.f};
  f32x4 acc2 = {0.f, 0.f, 0.f, 0.f};
  f32x4 acc3 = {0.f, 0.f, 0.f, 0.f};
  int e = e0;
  for (; e + 3 < e1; e += 4) {
    int s0 = cs[e], s1 = cs[e + 1], s2 = cs[e + 2], s3 = cs[e + 3];
    u16x4 v0 = *(const u16x4*)(hg + (size_t)s0 * F + lane * 4);
    u16x4 v1 = *(const u16x4*)(hg + (size_t)s1 * F + lane * 4);
    u16x4 v2 = *(const u16x4*)(hg + (size_t)s2 * F + lane * 4);
    u16x4 v3 = *(const u16x4*)(hg + (size_t)s3 * F + lane * 4);
    acc0 += cvt4(v0);
    acc1 += cvt4(v1);
    acc2 += cvt4(v2);
    acc3 += cvt4(v3);
  }
  for (; e < e1; ++e) {
    int s = cs[e];
    acc0 += cvt4(*(const u16x4*)(hg + (size_t)s * F + lane * 4));
  }
  f32x4 acc = (acc0 + acc1) + (acc2 + acc3);
  float4_t bb = *(const float4_t*)(bias + lane * 4);
  float4_t o;
  #pragma unroll
  for (int j = 0; j < 4; ++j) o[j] = fmaxf(fmaf(acc[j], di, bb[j]), 0.f);
  *(float4_t*)(outg + (size_t)node * F + lane * 4) = o;
}

// ---------------- host launch ----------------

extern "C" void kernel_launch(void* const* d_in, const int* in_sizes, int n_in,
                              void* d_out, int out_size, void* d_ws, size_t ws_size,
                              hipStream_t stream) {
  const float* x     = (const float*)d_in[0];
  const int*   edges = (const int*)d_in[1];
  const float* Ws[3] = {(const float*)d_in[2], (const float*)d_in[4], (const float*)d_in[6]};
  const float* bs[3] = {(const float*)d_in[3], (const float*)d_in[5], (const float*)d_in[7]};
  float* out = (float*)d_out;

  size_t sz_h1  = (size_t)NN * F * 2;           // 12.8 MB bf16 per graph
  size_t sz_wt  = (size_t)3 * 2 * F * F * 2;    // 196608 B
  size_t sz_csr = (size_t)EE * 4;
  size_t sz_deg = (size_t)NN * 4;
  size_t sz_dv  = (size_t)NN * 4;
  size_t sz_ro  = (size_t)(NN + 1) * 4;
  size_t per_g  = sz_h1 + sz_csr + sz_deg + sz_dv + sz_ro;  // ~16.5 MB

  int CB = (int)((ws_size > sz_wt ? ws_size - sz_wt : 0) / per_g);
  if (CB < 1) CB = 1;
  if (CB > G) CB = G;

  char* p = (char*)d_ws;
  unsigned short* h1      = (unsigned short*)p;  p += sz_h1 * CB;
  __bf16*         wt      = (__bf16*)p;          p += sz_wt;
  int*            csr     = (int*)p;             p += sz_csr * CB;
  int*            deg     = (int*)p;             p += sz_deg * CB;   // doubles as cursor
  float*          dinv    = (float*)p;           p += sz_dv  * CB;
  int*            row_off = (int*)p;

  wtprep_kernel<<<3, 256, 0, stream>>>(Ws[0], Ws[1], Ws[2], wt);

  int nblk_g = (NN + 63) / 64;   // 782
  int nblk_a = (NN + 7) / 8;     // 6250

  for (int gb = 0; gb < G; gb += CB) {
    int Cg = G - gb < CB ? G - gb : CB;
    hipMemsetAsync(deg, 0, (size_t)Cg * NN * 4, stream);
    deg_kernel <<<dim3(EE / 256, Cg), 256, 0, stream>>>(edges, deg, gb);
    scan_kernel<<<Cg, 1024, 0, stream>>>(deg, row_off, dinv);
    fill_kernel<<<dim3(EE / 256, Cg), 256, 0, stream>>>(edges, deg, row_off, csr, gb);
    for (int l = 0; l < 3; ++l) {
      const float* act = (l == 0) ? x : (const float*)out;
      gemm_kernel<<<dim3(nblk_g, Cg), 256, 0, stream>>>(act, wt + (size_t)l * 2 * F * F,
                                                        dinv, h1, gb);
      agg_kernel <<<dim3(nblk_a, Cg), 256, 0, stream>>>(h1, csr, row_off, dinv, bs[l], out, gb);
    }
  }
}